// Round 19
// baseline (206.640 us; speedup 1.0000x reference)
//
#include <hip/hip_runtime.h>
#include <hip/hip_bf16.h>
#include <hip/hip_fp8.h>

constexpr int NN = 100000;
constexpr int NE = 1600000;

constexpr int SH1  = 9;                      // 512 nodes per bucket
constexpr int NB1  = (NN + 511) >> SH1;      // 196 buckets
constexpr int EB   = 8192;                   // edges per pass-A block
constexpr int NBLK = (NE + EB - 1) / EB;     // 196 blocks
constexpr int NH   = NB1 * NBLK;             // 38416 histogram cells

constexpr float FP8_SCL  = 128.f;
constexpr float FP8_ISCL = 1.f / 128.f;

typedef __bf16 bf16_t;
typedef bf16_t bf16x8 __attribute__((ext_vector_type(8)));
typedef bf16_t bf16x4 __attribute__((ext_vector_type(4)));
typedef float  f32x4  __attribute__((ext_vector_type(4)));
typedef float  f32x2  __attribute__((ext_vector_type(2)));

// fast ELU: exp via v_exp_f32 (HW transcendental), ~1e-5 rel err vs expm1f
__device__ inline float elu_fast(float v) {
  return v > 0.f ? v : (__expf(v) - 1.f);
}

// fp8 helpers (sel/word-half must be literal -> template parameters)
__device__ inline unsigned char f_to_fp8(float v) {
  __hip_fp8_e4m3 q(v);
  return q.__x;
}
template<int SEL>
__device__ inline float fp8_to_f(unsigned int word) {
#if __has_builtin(__builtin_amdgcn_cvt_f32_fp8)
  return __builtin_amdgcn_cvt_f32_fp8(word, SEL);
#else
  __hip_fp8_e4m3 t; t.__x = (word >> (8 * SEL)) & 0xff; return (float)t;
#endif
}
template<bool W>
__device__ inline f32x2 fp8pk2(unsigned int word) {
#if __has_builtin(__builtin_amdgcn_cvt_pk_f32_fp8)
  return __builtin_amdgcn_cvt_pk_f32_fp8((int)word, W);
#else
  f32x2 o; o.x = fp8_to_f<W ? 2 : 0>(word); o.y = fp8_to_f<W ? 3 : 1>(word); return o;
#endif
}
// decode 8 packed fp8 (uint2) and ADD into acc[8] (dinv pre-folded into table)
__device__ inline void fp8x8_add(float* acc, uint2 v) {
  f32x2 p0 = fp8pk2<false>(v.x);
  f32x2 p1 = fp8pk2<true >(v.x);
  f32x2 p2 = fp8pk2<false>(v.y);
  f32x2 p3 = fp8pk2<true >(v.y);
  acc[0] += p0.x; acc[1] += p0.y;
  acc[2] += p1.x; acc[3] += p1.y;
  acc[4] += p2.x; acc[5] += p2.y;
  acc[6] += p3.x; acc[7] += p3.y;
}
__device__ inline void fp8x8_fma(float* acc, uint2 v, float s) {
  f32x2 p0 = fp8pk2<false>(v.x);
  f32x2 p1 = fp8pk2<true >(v.x);
  f32x2 p2 = fp8pk2<false>(v.y);
  f32x2 p3 = fp8pk2<true >(v.y);
  acc[0] += p0.x * s; acc[1] += p0.y * s;
  acc[2] += p1.x * s; acc[3] += p1.y * s;
  acc[4] += p2.x * s; acc[5] += p2.y * s;
  acc[6] += p3.x * s; acc[7] += p3.y * s;
}

// ---------------- generic scan chain (used for H only) ----------------
constexpr int SB = 256;

__global__ void scan_blk(const int* __restrict__ in, int* __restrict__ incl,
                         int* __restrict__ bsum, int n) {
  __shared__ int sm[SB];
  int i = blockIdx.x * SB + threadIdx.x;
  int v = (i < n) ? in[i] : 0;
  sm[threadIdx.x] = v;
  __syncthreads();
  for (int off = 1; off < SB; off <<= 1) {
    int t = (threadIdx.x >= off) ? sm[threadIdx.x - off] : 0;
    __syncthreads();
    sm[threadIdx.x] += t;
    __syncthreads();
  }
  if (i < n) incl[i] = sm[threadIdx.x];
  if (threadIdx.x == SB - 1) bsum[blockIdx.x] = sm[SB - 1];
}

__global__ void scan_top(int* __restrict__ bsum, int nb) {
  __shared__ int sm[512];
  int t = threadIdx.x;
  int v = (t < nb) ? bsum[t] : 0;
  sm[t] = v;
  __syncthreads();
  for (int off = 1; off < 512; off <<= 1) {
    int u = (t >= off) ? sm[t - off] : 0;
    __syncthreads();
    sm[t] += u;
    __syncthreads();
  }
  if (t < nb) bsum[t] = sm[t] - v;   // exclusive
}

// scan finalize for H; also emits boff (bucket bases: Hoff at i % NBLK == 0)
__global__ void scan_add_h(const int* __restrict__ incl, const int* __restrict__ in,
                           const int* __restrict__ bsum, int* __restrict__ Hoff,
                           int* __restrict__ boff, int n) {
  int i = blockIdx.x * SB + threadIdx.x;
  if (i < n) {
    int off = bsum[blockIdx.x];
    int ex = off + incl[i] - in[i];    // exclusive prefix
    Hoff[i] = ex;
    if (i % NBLK == 0) boff[i / NBLK] = ex;
    if (i == n - 1) { Hoff[n] = NE; boff[NB1] = NE; }
  }
}

// ---------------- pass A: block-local histogram + owned-range scatter ----------------

__global__ __launch_bounds__(256) void histA(const int* __restrict__ dst,
                                             int* __restrict__ H, int e) {
  __shared__ int h[NB1];
  for (int i = threadIdx.x; i < NB1; i += 256) h[i] = 0;
  __syncthreads();
  int base = blockIdx.x * EB;
  int end = min(base + EB, e);
  for (int i = base + threadIdx.x; i < end; i += 256)
    atomicAdd(&h[dst[i] >> SH1], 1);
  __syncthreads();
  for (int i = threadIdx.x; i < NB1; i += 256)
    H[i * NBLK + blockIdx.x] = h[i];
}

// packed ebuf entry: (dst&511)<<17 | src  (26 bits, 4 B)
__global__ __launch_bounds__(256) void scatterA(
    const int* __restrict__ src, const int* __restrict__ dst,
    const int* __restrict__ Hoff, unsigned int* __restrict__ ebuf, int e) {
  __shared__ int cur[NB1];
  for (int i = threadIdx.x; i < NB1; i += 256)
    cur[i] = Hoff[i * NBLK + blockIdx.x];
  __syncthreads();
  int base = blockIdx.x * EB;
  int end = min(base + EB, e);
  for (int i = base + threadIdx.x; i < end; i += 256) {
    int d = dst[i], s = src[i];
    int pos = atomicAdd(&cur[d >> SH1], 1);
    ebuf[pos] = ((unsigned)(d & 511) << 17) | (unsigned)s;
  }
}

// ---------------- pass B fused: degree + scan + row_off + dinv + placement ----------------

__global__ __launch_bounds__(512) void bfin(const unsigned int* __restrict__ ebuf,
                                            const int* __restrict__ boff,
                                            int* __restrict__ row_off, float* __restrict__ dinv,
                                            int* __restrict__ csr, int n) {
  __shared__ int cnt[512];
  __shared__ int loc[512];
  const int tid = threadIdx.x;
  const int b = blockIdx.x;
  cnt[tid] = 0;
  __syncthreads();
  const int e0 = boff[b], e1 = boff[b + 1];
  for (int e = e0 + tid; e < e1; e += 512)
    atomicAdd(&cnt[ebuf[e] >> 17], 1);
  __syncthreads();
  loc[tid] = cnt[tid];
  __syncthreads();
  for (int off = 1; off < 512; off <<= 1) {
    int t = (tid >= off) ? loc[tid - off] : 0;
    __syncthreads();
    loc[tid] += t;
    __syncthreads();
  }
  const int excl = loc[tid] - cnt[tid];
  const int node = (b << SH1) + tid;
  if (node < n) {
    row_off[node] = boff[b] + excl;
    dinv[node] = rsqrtf((float)cnt[tid] + 1.0f);   // +1 self-loop
  }
  if (b == NB1 - 1 && tid == 0) row_off[n] = NE;
  cnt[tid] = boff[b] + excl;
  __syncthreads();
  for (int e = e0 + tid; e < e1; e += 512) {
    unsigned int v = ebuf[e];
    int dl = (int)(v >> 17);
    int s  = (int)(v & 0x1FFFFu);
    int slot = atomicAdd(&cnt[dl], 1);
    csr[slot] = s;
  }
}

// ---------------- misc ----------------

// edges (2*NE ints) then batch (NN ints) -> float, one launch
__global__ void i2f_all(const int4* __restrict__ e4, const int4* __restrict__ b4,
                        float4* __restrict__ out, int ne4, int ntot4) {
  int i = blockIdx.x * blockDim.x + threadIdx.x;
  if (i >= ntot4) return;
  int4 v = (i < ne4) ? e4[i] : b4[i - ne4];
  out[i] = make_float4((float)v.x, (float)v.y, (float)v.z, (float)v.w);
}

// all four weight shuffles in one launch. grid = 320*256 = 81920 exactly.
__global__ void wprep4(const float* __restrict__ W1, const float* __restrict__ W2,
                       const float* __restrict__ Wgc, const float* __restrict__ Wc,
                       bf16_t* __restrict__ Wf) {
  int idx = blockIdx.x * blockDim.x + threadIdx.x;
  const float* W; int base;
  if      (idx < 8192)  { W = W1;  base = 0; }
  else if (idx < 24576) { W = W2;  base = 8192; }
  else if (idx < 49152) { W = Wgc; base = 24576; }
  else                  { W = Wc;  base = 49152; }
  int il   = idx - base;
  int j    = il & 7;
  int lane = (il >> 3) & 63;
  int c    = (il >> 9) & 7;
  int kt   = il >> 12;
  int k    = kt * 32 + (lane >> 4) * 8 + j;
  int col  = c * 16 + (lane & 15);
  Wf[idx] = (bf16_t)W[(size_t)k * 128 + col];
}

// ---------------- fused dense layers 1+2+GCN-linear, reg-prefetched W staging ----------------
// T14 async-stage split: issue chunk ch+1's global loads into regs BEFORE computing
// chunk ch from LDS; after compute, barrier -> ds_write regs -> barrier.
__global__ __launch_bounds__(256) void mf_dense123(
    const float* __restrict__ A, const bf16_t* __restrict__ Wall,
    const float* __restrict__ b1, const float* __restrict__ b2,
    const float* __restrict__ dinv_g,
    bf16_t* __restrict__ h2out, unsigned char* __restrict__ xqout, int n)
{
  __shared__ __align__(16) char h1s[64 * 256];   // 16KB: 64 rows x 128 bf16
  __shared__ __align__(16) char wbuf[16384];     // 16KB: one chunk = 2 kt of W frags
  const int tid  = threadIdx.x;
  const int wv   = tid >> 6;
  const int lane = tid & 63;
  const int r    = lane & 15;
  const int kb   = lane >> 4;
  const int row0 = blockIdx.x * 64 + wv * 16;

  f32x4 acc[8];
  #pragma unroll
  for (int c = 0; c < 8; ++c) acc[c] = (f32x4){0.f, 0.f, 0.f, 0.f};

  int rowA = row0 + r; if (rowA >= n) rowA = n - 1;
  const int rloc = wv * 16 + r;

  // prologue: stage chunk 0
  {
    #pragma unroll
    for (int k = 0; k < 4; ++k) {
      float4 v = *(const float4*)((const char*)Wall + k * 4096 + tid * 16);
      *(float4*)(wbuf + k * 4096 + tid * 16) = v;
    }
  }
  __syncthreads();

  for (int ch = 0; ch < 6; ++ch) {
    // issue next chunk's loads early (latency hides under compute below)
    float4 nxt[4];
    if (ch < 5) {
      const char* src = (const char*)Wall + (ch + 1) * 16384;
      #pragma unroll
      for (int k = 0; k < 4; ++k)
        nxt[k] = *(const float4*)(src + k * 4096 + tid * 16);
    }

    #pragma unroll
    for (int lk = 0; lk < 2; ++lk) {
      const int gkt = ch * 2 + lk;
      bf16x8 a;
      if (gkt < 2) {                              // phase 1: feats f32
        const float* fp = A + (size_t)rowA * 64 + gkt * 32 + kb * 8;
        float4 u = *(const float4*)fp;
        float4 v = *(const float4*)(fp + 4);
        a = (bf16x8){(bf16_t)u.x, (bf16_t)u.y, (bf16_t)u.z, (bf16_t)u.w,
                     (bf16_t)v.x, (bf16_t)v.y, (bf16_t)v.z, (bf16_t)v.w};
      } else if (gkt < 6) {                       // phase 2: h1 from LDS
        int kbyte = ((gkt - 2) * 32 + kb * 8) * 2;
        int off = (rloc * 256 + kbyte) ^ ((rloc & 7) << 4);
        a = *(const bf16x8*)(h1s + off);
      } else {                                    // phase 3: h2 LDS ++ feats
        int kofs = (gkt - 6) * 32 + kb * 8;
        if (kofs < 128) {
          int off = (rloc * 256 + kofs * 2) ^ ((rloc & 7) << 4);
          a = *(const bf16x8*)(h1s + off);
        } else {
          const float* fp = A + (size_t)rowA * 64 + (kofs - 128);
          float4 u = *(const float4*)fp;
          float4 v = *(const float4*)(fp + 4);
          a = (bf16x8){(bf16_t)u.x, (bf16_t)u.y, (bf16_t)u.z, (bf16_t)u.w,
                       (bf16_t)v.x, (bf16_t)v.y, (bf16_t)v.z, (bf16_t)v.w};
        }
      }
      #pragma unroll
      for (int c = 0; c < 8; ++c) {
        bf16x8 b = *(const bf16x8*)(wbuf + ((lk * 8 + c) * 64 + lane) * 16);
        acc[c] = __builtin_amdgcn_mfma_f32_16x16x32_bf16(a, b, acc[c], 0, 0, 0);
      }
      if (gkt == 1) {
        #pragma unroll
        for (int c = 0; c < 8; ++c) {
          const int col = c * 16 + r;
          const float bv = b1[col];
          #pragma unroll
          for (int q = 0; q < 4; ++q) {
            int rl = wv * 16 + kb * 4 + q;
            float v = elu_fast(acc[c][q] + bv);
            int off = (rl * 256 + col * 2) ^ ((rl & 7) << 4);
            *(bf16_t*)(h1s + off) = (bf16_t)v;
          }
          acc[c] = (f32x4){0.f, 0.f, 0.f, 0.f};
        }
      } else if (gkt == 5) {
        #pragma unroll
        for (int c = 0; c < 8; ++c) {
          const int col = c * 16 + r;
          const float bv = b2[col];
          #pragma unroll
          for (int q = 0; q < 4; ++q) {
            int row = row0 + kb * 4 + q;
            int rl  = wv * 16 + kb * 4 + q;
            float v = elu_fast(acc[c][q] + bv);
            int off = (rl * 256 + col * 2) ^ ((rl & 7) << 4);
            *(bf16_t*)(h1s + off) = (bf16_t)v;
            if (row < n) h2out[(size_t)row * 128 + col] = (bf16_t)v;
          }
          acc[c] = (f32x4){0.f, 0.f, 0.f, 0.f};
        }
      }
    }

    // publish next chunk
    if (ch < 5) {
      __syncthreads();   // all waves done reading wbuf
      #pragma unroll
      for (int k = 0; k < 4; ++k)
        *(float4*)(wbuf + k * 4096 + tid * 16) = nxt[k];
      __syncthreads();   // visible
    }
  }

  // epilogue 3: fp8 out, scaled x128 and PRESCALED by dinv[row]
  float dv[4];
  #pragma unroll
  for (int q = 0; q < 4; ++q) {
    int row = row0 + kb * 4 + q;
    dv[q] = (row < n) ? dinv_g[row] * FP8_SCL : 0.f;
  }
  #pragma unroll
  for (int c = 0; c < 8; ++c) {
    const int col = c * 16 + r;
    #pragma unroll
    for (int q = 0; q < 4; ++q) {
      int row = row0 + kb * 4 + q;
      if (row < n)
        xqout[(size_t)row * 128 + col] = f_to_fp8(acc[c][q] * dv[q]);
    }
  }
}

// ---------------- final output layer, reg-prefetched W staging (K=256, 4 chunks) ----------------
__global__ __launch_bounds__(256) void mf_dense_s(
    const bf16_t* __restrict__ A1, const bf16_t* __restrict__ A2,
    const bf16_t* __restrict__ Wf, const float* __restrict__ bias,
    float* __restrict__ outf, int n)
{
  __shared__ __align__(16) char wbuf[16384];
  const int tid  = threadIdx.x;
  const int wv   = tid >> 6;
  const int lane = tid & 63;
  const int r    = lane & 15;
  const int kb   = lane >> 4;
  const int row0 = blockIdx.x * 64 + wv * 16;

  f32x4 acc[8];
  #pragma unroll
  for (int c = 0; c < 8; ++c) acc[c] = (f32x4){0.f, 0.f, 0.f, 0.f};

  int rowA = row0 + r; if (rowA >= n) rowA = n - 1;

  {
    #pragma unroll
    for (int k = 0; k < 4; ++k) {
      float4 v = *(const float4*)((const char*)Wf + k * 4096 + tid * 16);
      *(float4*)(wbuf + k * 4096 + tid * 16) = v;
    }
  }
  __syncthreads();

  for (int ch = 0; ch < 4; ++ch) {
    float4 nxt[4];
    if (ch < 3) {
      const char* src = (const char*)Wf + (ch + 1) * 16384;
      #pragma unroll
      for (int k = 0; k < 4; ++k)
        nxt[k] = *(const float4*)(src + k * 4096 + tid * 16);
    }

    #pragma unroll
    for (int lk = 0; lk < 2; ++lk) {
      const int gkt = ch * 2 + lk;
      bf16x8 a;
      if (gkt < 4) a = *(const bf16x8*)(A1 + (size_t)rowA * 128 + gkt * 32 + kb * 8);
      else         a = *(const bf16x8*)(A2 + (size_t)rowA * 128 + (gkt - 4) * 32 + kb * 8);
      #pragma unroll
      for (int c = 0; c < 8; ++c) {
        bf16x8 b = *(const bf16x8*)(wbuf + ((lk * 8 + c) * 64 + lane) * 16);
        acc[c] = __builtin_amdgcn_mfma_f32_16x16x32_bf16(a, b, acc[c], 0, 0, 0);
      }
    }

    if (ch < 3) {
      __syncthreads();
      #pragma unroll
      for (int k = 0; k < 4; ++k)
        *(float4*)(wbuf + k * 4096 + tid * 16) = nxt[k];
      __syncthreads();
    }
  }

  #pragma unroll
  for (int c = 0; c < 8; ++c) {
    const int col = c * 16 + r;
    const float bv = bias[col];
    #pragma unroll
    for (int q = 0; q < 4; ++q) {
      int row = row0 + kb * 4 + q;
      if (row < n) {
        float v = elu_fast(acc[c][q] + bv);
        outf[(size_t)row * 128 + col] = v;
      }
    }
  }
}

// ---------------- GCN aggregate v9: fp8 table, 16-edge main + 8-edge mid + masked tail ----------------
// xq[s] already = xg[s]*dinv[s]*128. agg[d] = dinv[d]/128 * ( sum_s xq[s] + xq[d] ) + bgc
__global__ __launch_bounds__(256) void gcn_agg9(
    const int* __restrict__ row_off, const int* __restrict__ csr,
    const float* __restrict__ dinv, const unsigned char* __restrict__ xq,
    const float* __restrict__ bgc, bf16_t* __restrict__ agg, int n)
{
  int w = (int)((blockIdx.x * (unsigned)blockDim.x + threadIdx.x) >> 6);
  if (w >= n) return;
  const int lane = threadIdx.x & 63;
  const int g  = lane >> 4;     // edge subgroup 0..3
  const int li = lane & 15;     // feature octet: cols 8*li .. 8*li+7

  float acc[8];
  #pragma unroll
  for (int j = 0; j < 8; ++j) acc[j] = 0.f;

  if (g == 0) {
    uint2 sv = ((const uint2*)(xq + (size_t)w * 128))[li];
    fp8x8_add(acc, sv);     // self-loop term (dinv[w] already folded)
  }

  const int e0 = row_off[w], e1 = row_off[w + 1];
  int e = e0;
  for (; e + 16 <= e1; e += 16) {
    #pragma unroll
    for (int u = 0; u < 4; ++u) {
      int s = csr[e + 4 * u + g];
      uint2 v = ((const uint2*)(xq + (size_t)s * 128))[li];
      fp8x8_add(acc, v);
    }
  }
  if (e + 8 <= e1) {
    #pragma unroll
    for (int u = 0; u < 2; ++u) {
      int s = csr[e + 4 * u + g];
      uint2 v = ((const uint2*)(xq + (size_t)s * 128))[li];
      fp8x8_add(acc, v);
    }
    e += 8;
  }
  for (; e < e1; e += 4) {
    int idx = e + g;
    int cidx = idx < e1 ? idx : e1 - 1;
    int s = csr[cidx];
    float coef = idx < e1 ? 1.f : 0.f;
    uint2 v = ((const uint2*)(xq + (size_t)s * 128))[li];
    fp8x8_fma(acc, v, coef);
  }

  #pragma unroll
  for (int j = 0; j < 8; ++j) {
    acc[j] += __shfl_xor(acc[j], 16);
    acc[j] += __shfl_xor(acc[j], 32);
  }

  if (g == 0) {
    const float sc = dinv[w] * FP8_ISCL;
    f32x4 b0 = ((const f32x4*)bgc)[2 * li];
    f32x4 b1 = ((const f32x4*)bgc)[2 * li + 1];
    bf16x8 o;
    o[0] = (bf16_t)(acc[0] * sc + b0[0]); o[1] = (bf16_t)(acc[1] * sc + b0[1]);
    o[2] = (bf16_t)(acc[2] * sc + b0[2]); o[3] = (bf16_t)(acc[3] * sc + b0[3]);
    o[4] = (bf16_t)(acc[4] * sc + b1[0]); o[5] = (bf16_t)(acc[5] * sc + b1[1]);
    o[6] = (bf16_t)(acc[6] * sc + b1[2]); o[7] = (bf16_t)(acc[7] * sc + b1[3]);
    ((bf16x8*)(agg + (size_t)w * 128))[li] = o;
  }
}

// ---------------- launch ----------------

extern "C" void kernel_launch(void* const* d_in, const int* in_sizes, int n_in,
                              void* d_out, int out_size, void* d_ws, size_t ws_size,
                              hipStream_t stream) {
  (void)in_sizes; (void)n_in; (void)out_size; (void)ws_size;
  const float* feats = (const float*)d_in[0];
  const int*   edges = (const int*)d_in[1];
  const int*   batch = (const int*)d_in[2];
  const float* W1  = (const float*)d_in[3];
  const float* b1  = (const float*)d_in[4];
  const float* W2  = (const float*)d_in[5];
  const float* b2  = (const float*)d_in[6];
  const float* Wgc = (const float*)d_in[7];
  const float* bgc = (const float*)d_in[8];
  const float* Wc  = (const float*)d_in[9];
  const float* bc  = (const float*)d_in[10];
  float* out = (float*)d_out;

  // workspace layout
  bf16_t* h2b  = (bf16_t*)d_ws;                      // [NN*128] bf16 (nfeats)
  bf16_t* aggb = h2b  + (size_t)NN * 128;            // [NN*128] bf16
  unsigned char* xq8 = (unsigned char*)(aggb + (size_t)NN * 128);  // [NN*128] fp8
  float*  dinv = (float*)(xq8 + (size_t)NN * 128);   // [NN]
  bf16_t* wall = (bf16_t*)(dinv + NN);               // [81920] frag-ordered Ws
  bf16_t* wcf  = wall + 49152;

  // scratch in the FRONT of d_out (dead before final mf_dense_s writes it)
  int* scr     = (int*)d_out;
  int* csr_src = scr;                   // [NE]
  int* row_off = csr_src + NE;          // [NN+1]
  int* H       = row_off + NN + 1;      // [NH]
  int* Hincl   = H + NH;                // [NH]
  int* Hoff    = Hincl + NH;            // [NH+1]
  int* boff    = Hoff + NH + 1;         // [NB1+1]
  int* bsum2   = boff + NB1 + 1;        // [512]
  unsigned int* ebuf = (unsigned int*)(bsum2 + 512);  // [NE] packed (dl<<17|src)

  const int* esrc = edges;
  const int* edst = edges + NE;

  const int nscH = (NH + SB - 1) / SB;   // 151

  // --- CSR build: block-owned bucket sort + fused finalize ---
  histA     <<<NBLK, 256, 0, stream>>>(edst, H, NE);
  scan_blk  <<<nscH, SB, 0, stream>>>(H, Hincl, bsum2, NH);
  scan_top  <<<1, 512, 0, stream>>>(bsum2, nscH);
  scan_add_h<<<nscH, SB, 0, stream>>>(Hincl, H, bsum2, Hoff, boff, NH);
  scatterA  <<<NBLK, 256, 0, stream>>>(esrc, edst, Hoff, ebuf, NE);
  bfin      <<<NB1, 512, 0, stream>>>(ebuf, boff, row_off, dinv, csr_src, NN);

  // --- weight prep (single launch) ---
  wprep4<<<320, 256, 0, stream>>>(W1, W2, Wgc, Wc, wall);

  // --- fused dense 1+2+GCN-linear (64 rows/block, 16 rows/wave, prefetched LDS W) ---
  const int nb = (NN + 63) / 64;   // 1563
  mf_dense123<<<nb, 256, 0, stream>>>(feats, wall, b1, b2, dinv, h2b, xq8, NN);

  // --- GCN aggregate (fp8 gather, v9) ---
  long long wthreads = (long long)NN * 64;
  gcn_agg9<<<(int)((wthreads + 255) / 256), 256, 0, stream>>>(
      row_off, csr_src, dinv, xq8, bgc, aggb, NN);

  // --- output layer (fp32 into d_out, overwrites scratch; prefetched LDS W) ---
  mf_dense_s<<<nb, 256, 0, stream>>>(h2b, aggb, wcf, bc, out, NN);

  // tail outputs: edges then batch, as float, one launch
  size_t off = (size_t)NN * 128;
  const int ne4 = 2 * NE / 4, ntot4 = (2 * NE + NN) / 4;
  i2f_all<<<(ntot4 + 255) / 256, 256, 0, stream>>>(
      (const int4*)edges, (const int4*)batch, (float4*)(out + off), ne4, ntot4);
}

// Round 20
// 168.850 us; speedup vs baseline: 1.2238x; 1.2238x over previous
//
#include <hip/hip_runtime.h>
#include <hip/hip_bf16.h>
#include <hip/hip_fp8.h>

constexpr int NN = 100000;
constexpr int NE = 1600000;

constexpr int SH1  = 9;                      // 512 nodes per bucket
constexpr int NB1  = (NN + 511) >> SH1;      // 196 buckets
constexpr int EB   = 8192;                   // edges per pass-A block
constexpr int NBLK = (NE + EB - 1) / EB;     // 196 blocks
constexpr int NH   = NB1 * NBLK;             // 38416 histogram cells

constexpr float FP8_SCL  = 128.f;
constexpr float FP8_ISCL = 1.f / 128.f;

typedef __bf16 bf16_t;
typedef bf16_t bf16x8 __attribute__((ext_vector_type(8)));
typedef bf16_t bf16x4 __attribute__((ext_vector_type(4)));
typedef float  f32x4  __attribute__((ext_vector_type(4)));
typedef float  f32x2  __attribute__((ext_vector_type(2)));

// fast ELU: exp via v_exp_f32 (HW transcendental), ~1e-5 rel err vs expm1f
__device__ inline float elu_fast(float v) {
  return v > 0.f ? v : (__expf(v) - 1.f);
}

// fp8 helpers (sel/word-half must be literal -> template parameters)
__device__ inline unsigned char f_to_fp8(float v) {
  __hip_fp8_e4m3 q(v);
  return q.__x;
}
template<int SEL>
__device__ inline float fp8_to_f(unsigned int word) {
#if __has_builtin(__builtin_amdgcn_cvt_f32_fp8)
  return __builtin_amdgcn_cvt_f32_fp8(word, SEL);
#else
  __hip_fp8_e4m3 t; t.__x = (word >> (8 * SEL)) & 0xff; return (float)t;
#endif
}
template<bool W>
__device__ inline f32x2 fp8pk2(unsigned int word) {
#if __has_builtin(__builtin_amdgcn_cvt_pk_f32_fp8)
  return __builtin_amdgcn_cvt_pk_f32_fp8((int)word, W);
#else
  f32x2 o; o.x = fp8_to_f<W ? 2 : 0>(word); o.y = fp8_to_f<W ? 3 : 1>(word); return o;
#endif
}
// decode 8 packed fp8 (uint2) and ADD into acc[8] (dinv pre-folded into table)
__device__ inline void fp8x8_add(float* acc, uint2 v) {
  f32x2 p0 = fp8pk2<false>(v.x);
  f32x2 p1 = fp8pk2<true >(v.x);
  f32x2 p2 = fp8pk2<false>(v.y);
  f32x2 p3 = fp8pk2<true >(v.y);
  acc[0] += p0.x; acc[1] += p0.y;
  acc[2] += p1.x; acc[3] += p1.y;
  acc[4] += p2.x; acc[5] += p2.y;
  acc[6] += p3.x; acc[7] += p3.y;
}
__device__ inline void fp8x8_fma(float* acc, uint2 v, float s) {
  f32x2 p0 = fp8pk2<false>(v.x);
  f32x2 p1 = fp8pk2<true >(v.x);
  f32x2 p2 = fp8pk2<false>(v.y);
  f32x2 p3 = fp8pk2<true >(v.y);
  acc[0] += p0.x * s; acc[1] += p0.y * s;
  acc[2] += p1.x * s; acc[3] += p1.y * s;
  acc[4] += p2.x * s; acc[5] += p2.y * s;
  acc[6] += p3.x * s; acc[7] += p3.y * s;
}

// ---------------- generic scan chain (used for H only) ----------------
constexpr int SB = 256;

__global__ void scan_blk(const int* __restrict__ in, int* __restrict__ incl,
                         int* __restrict__ bsum, int n) {
  __shared__ int sm[SB];
  int i = blockIdx.x * SB + threadIdx.x;
  int v = (i < n) ? in[i] : 0;
  sm[threadIdx.x] = v;
  __syncthreads();
  for (int off = 1; off < SB; off <<= 1) {
    int t = (threadIdx.x >= off) ? sm[threadIdx.x - off] : 0;
    __syncthreads();
    sm[threadIdx.x] += t;
    __syncthreads();
  }
  if (i < n) incl[i] = sm[threadIdx.x];
  if (threadIdx.x == SB - 1) bsum[blockIdx.x] = sm[SB - 1];
}

__global__ void scan_top(int* __restrict__ bsum, int nb) {
  __shared__ int sm[512];
  int t = threadIdx.x;
  int v = (t < nb) ? bsum[t] : 0;
  sm[t] = v;
  __syncthreads();
  for (int off = 1; off < 512; off <<= 1) {
    int u = (t >= off) ? sm[t - off] : 0;
    __syncthreads();
    sm[t] += u;
    __syncthreads();
  }
  if (t < nb) bsum[t] = sm[t] - v;   // exclusive
}

// scan finalize for H; also emits boff (bucket bases: Hoff at i % NBLK == 0)
__global__ void scan_add_h(const int* __restrict__ incl, const int* __restrict__ in,
                           const int* __restrict__ bsum, int* __restrict__ Hoff,
                           int* __restrict__ boff, int n) {
  int i = blockIdx.x * SB + threadIdx.x;
  if (i < n) {
    int off = bsum[blockIdx.x];
    int ex = off + incl[i] - in[i];    // exclusive prefix
    Hoff[i] = ex;
    if (i % NBLK == 0) boff[i / NBLK] = ex;
    if (i == n - 1) { Hoff[n] = NE; boff[NB1] = NE; }
  }
}

// ---------------- pass A: block-local histogram + owned-range scatter ----------------

__global__ __launch_bounds__(256) void histA(const int* __restrict__ dst,
                                             int* __restrict__ H, int e) {
  __shared__ int h[NB1];
  for (int i = threadIdx.x; i < NB1; i += 256) h[i] = 0;
  __syncthreads();
  int base = blockIdx.x * EB;
  int end = min(base + EB, e);
  for (int i = base + threadIdx.x; i < end; i += 256)
    atomicAdd(&h[dst[i] >> SH1], 1);
  __syncthreads();
  for (int i = threadIdx.x; i < NB1; i += 256)
    H[i * NBLK + blockIdx.x] = h[i];
}

// packed ebuf entry: (dst&511)<<17 | src  (26 bits, 4 B)
__global__ __launch_bounds__(256) void scatterA(
    const int* __restrict__ src, const int* __restrict__ dst,
    const int* __restrict__ Hoff, unsigned int* __restrict__ ebuf, int e) {
  __shared__ int cur[NB1];
  for (int i = threadIdx.x; i < NB1; i += 256)
    cur[i] = Hoff[i * NBLK + blockIdx.x];
  __syncthreads();
  int base = blockIdx.x * EB;
  int end = min(base + EB, e);
  for (int i = base + threadIdx.x; i < end; i += 256) {
    int d = dst[i], s = src[i];
    int pos = atomicAdd(&cur[d >> SH1], 1);
    ebuf[pos] = ((unsigned)(d & 511) << 17) | (unsigned)s;
  }
}

// ---------------- pass B fused: degree + scan + row_off + dinv + placement ----------------

__global__ __launch_bounds__(512) void bfin(const unsigned int* __restrict__ ebuf,
                                            const int* __restrict__ boff,
                                            int* __restrict__ row_off, float* __restrict__ dinv,
                                            int* __restrict__ csr, int n) {
  __shared__ int cnt[512];
  __shared__ int loc[512];
  const int tid = threadIdx.x;
  const int b = blockIdx.x;
  cnt[tid] = 0;
  __syncthreads();
  const int e0 = boff[b], e1 = boff[b + 1];
  for (int e = e0 + tid; e < e1; e += 512)
    atomicAdd(&cnt[ebuf[e] >> 17], 1);
  __syncthreads();
  loc[tid] = cnt[tid];
  __syncthreads();
  for (int off = 1; off < 512; off <<= 1) {
    int t = (tid >= off) ? loc[tid - off] : 0;
    __syncthreads();
    loc[tid] += t;
    __syncthreads();
  }
  const int excl = loc[tid] - cnt[tid];
  const int node = (b << SH1) + tid;
  if (node < n) {
    row_off[node] = boff[b] + excl;
    dinv[node] = rsqrtf((float)cnt[tid] + 1.0f);   // +1 self-loop
  }
  if (b == NB1 - 1 && tid == 0) row_off[n] = NE;
  cnt[tid] = boff[b] + excl;
  __syncthreads();
  for (int e = e0 + tid; e < e1; e += 512) {
    unsigned int v = ebuf[e];
    int dl = (int)(v >> 17);
    int s  = (int)(v & 0x1FFFFu);
    int slot = atomicAdd(&cnt[dl], 1);
    csr[slot] = s;
  }
}

// ---------------- misc ----------------

// edges (2*NE ints) then batch (NN ints) -> float, one launch
__global__ void i2f_all(const int4* __restrict__ e4, const int4* __restrict__ b4,
                        float4* __restrict__ out, int ne4, int ntot4) {
  int i = blockIdx.x * blockDim.x + threadIdx.x;
  if (i >= ntot4) return;
  int4 v = (i < ne4) ? e4[i] : b4[i - ne4];
  out[i] = make_float4((float)v.x, (float)v.y, (float)v.z, (float)v.w);
}

// all four weight shuffles in one launch. grid = 320*256 = 81920 exactly.
__global__ void wprep4(const float* __restrict__ W1, const float* __restrict__ W2,
                       const float* __restrict__ Wgc, const float* __restrict__ Wc,
                       bf16_t* __restrict__ Wf) {
  int idx = blockIdx.x * blockDim.x + threadIdx.x;
  const float* W; int base;
  if      (idx < 8192)  { W = W1;  base = 0; }
  else if (idx < 24576) { W = W2;  base = 8192; }
  else if (idx < 49152) { W = Wgc; base = 24576; }
  else                  { W = Wc;  base = 49152; }
  int il   = idx - base;
  int j    = il & 7;
  int lane = (il >> 3) & 63;
  int c    = (il >> 9) & 7;
  int kt   = il >> 12;
  int k    = kt * 32 + (lane >> 4) * 8 + j;
  int col  = c * 16 + (lane & 15);
  Wf[idx] = (bf16_t)W[(size_t)k * 128 + col];
}

// ---------------- fused dense layers 1+2+GCN-linear with LDS-staged W ----------------
// Weight stream = wall[0 : 96KB) consumed strictly in order; staged in six 16KB
// chunks (2 kt-steps each). Simple stage->barrier->compute loop: implicit
// wave-level overlap (20 waves/CU) hides the stage latency; explicit reg
// prefetch (r19) and 2-tile ILP (r13) both REGRESSED — do not reintroduce.
__global__ __launch_bounds__(256) void mf_dense123(
    const float* __restrict__ A, const bf16_t* __restrict__ Wall,
    const float* __restrict__ b1, const float* __restrict__ b2,
    const float* __restrict__ dinv_g,
    bf16_t* __restrict__ h2out, unsigned char* __restrict__ xqout, int n)
{
  __shared__ __align__(16) char h1s[64 * 256];   // 16KB: 64 rows x 128 bf16
  __shared__ __align__(16) char wbuf[16384];     // 16KB: one chunk = 2 kt of W frags
  const int tid  = threadIdx.x;
  const int wv   = tid >> 6;
  const int lane = tid & 63;
  const int r    = lane & 15;
  const int kb   = lane >> 4;
  const int row0 = blockIdx.x * 64 + wv * 16;

  f32x4 acc[8];
  #pragma unroll
  for (int c = 0; c < 8; ++c) acc[c] = (f32x4){0.f, 0.f, 0.f, 0.f};

  int rowA = row0 + r; if (rowA >= n) rowA = n - 1;
  const int rloc = wv * 16 + r;

  for (int ch = 0; ch < 6; ++ch) {
    __syncthreads();   // all waves done reading previous chunk
    {
      const char* src = (const char*)Wall + ch * 16384;
      #pragma unroll
      for (int k = 0; k < 4; ++k) {
        float4 v = *(const float4*)(src + k * 4096 + tid * 16);
        *(float4*)(wbuf + k * 4096 + tid * 16) = v;
      }
    }
    __syncthreads();   // chunk visible

    #pragma unroll
    for (int lk = 0; lk < 2; ++lk) {
      const int gkt = ch * 2 + lk;
      bf16x8 a;
      if (gkt < 2) {                              // phase 1: feats f32
        const float* fp = A + (size_t)rowA * 64 + gkt * 32 + kb * 8;
        float4 u = *(const float4*)fp;
        float4 v = *(const float4*)(fp + 4);
        a = (bf16x8){(bf16_t)u.x, (bf16_t)u.y, (bf16_t)u.z, (bf16_t)u.w,
                     (bf16_t)v.x, (bf16_t)v.y, (bf16_t)v.z, (bf16_t)v.w};
      } else if (gkt < 6) {                       // phase 2: h1 from LDS
        int kbyte = ((gkt - 2) * 32 + kb * 8) * 2;
        int off = (rloc * 256 + kbyte) ^ ((rloc & 7) << 4);
        a = *(const bf16x8*)(h1s + off);
      } else {                                    // phase 3: h2 LDS ++ feats
        int kofs = (gkt - 6) * 32 + kb * 8;
        if (kofs < 128) {
          int off = (rloc * 256 + kofs * 2) ^ ((rloc & 7) << 4);
          a = *(const bf16x8*)(h1s + off);
        } else {
          const float* fp = A + (size_t)rowA * 64 + (kofs - 128);
          float4 u = *(const float4*)fp;
          float4 v = *(const float4*)(fp + 4);
          a = (bf16x8){(bf16_t)u.x, (bf16_t)u.y, (bf16_t)u.z, (bf16_t)u.w,
                       (bf16_t)v.x, (bf16_t)v.y, (bf16_t)v.z, (bf16_t)v.w};
        }
      }
      #pragma unroll
      for (int c = 0; c < 8; ++c) {
        bf16x8 b = *(const bf16x8*)(wbuf + ((lk * 8 + c) * 64 + lane) * 16);
        acc[c] = __builtin_amdgcn_mfma_f32_16x16x32_bf16(a, b, acc[c], 0, 0, 0);
      }
      if (gkt == 1) {
        #pragma unroll
        for (int c = 0; c < 8; ++c) {
          const int col = c * 16 + r;
          const float bv = b1[col];
          #pragma unroll
          for (int q = 0; q < 4; ++q) {
            int rl = wv * 16 + kb * 4 + q;
            float v = elu_fast(acc[c][q] + bv);
            int off = (rl * 256 + col * 2) ^ ((rl & 7) << 4);
            *(bf16_t*)(h1s + off) = (bf16_t)v;
          }
          acc[c] = (f32x4){0.f, 0.f, 0.f, 0.f};
        }
      } else if (gkt == 5) {
        #pragma unroll
        for (int c = 0; c < 8; ++c) {
          const int col = c * 16 + r;
          const float bv = b2[col];
          #pragma unroll
          for (int q = 0; q < 4; ++q) {
            int row = row0 + kb * 4 + q;
            int rl  = wv * 16 + kb * 4 + q;
            float v = elu_fast(acc[c][q] + bv);
            int off = (rl * 256 + col * 2) ^ ((rl & 7) << 4);
            *(bf16_t*)(h1s + off) = (bf16_t)v;
            if (row < n) h2out[(size_t)row * 128 + col] = (bf16_t)v;
          }
          acc[c] = (f32x4){0.f, 0.f, 0.f, 0.f};
        }
      }
    }
  }

  // epilogue 3: fp8 out, scaled x128 and PRESCALED by dinv[row]
  float dv[4];
  #pragma unroll
  for (int q = 0; q < 4; ++q) {
    int row = row0 + kb * 4 + q;
    dv[q] = (row < n) ? dinv_g[row] * FP8_SCL : 0.f;
  }
  #pragma unroll
  for (int c = 0; c < 8; ++c) {
    const int col = c * 16 + r;
    #pragma unroll
    for (int q = 0; q < 4; ++q) {
      int row = row0 + kb * 4 + q;
      if (row < n)
        xqout[(size_t)row * 128 + col] = f_to_fp8(acc[c][q] * dv[q]);
    }
  }
}

// ---------------- final output layer with LDS-staged W (K=256, 4 chunks) ----------------
__global__ __launch_bounds__(256) void mf_dense_s(
    const bf16_t* __restrict__ A1, const bf16_t* __restrict__ A2,
    const bf16_t* __restrict__ Wf, const float* __restrict__ bias,
    float* __restrict__ outf, int n)
{
  __shared__ __align__(16) char wbuf[16384];
  const int tid  = threadIdx.x;
  const int wv   = tid >> 6;
  const int lane = tid & 63;
  const int r    = lane & 15;
  const int kb   = lane >> 4;
  const int row0 = blockIdx.x * 64 + wv * 16;

  f32x4 acc[8];
  #pragma unroll
  for (int c = 0; c < 8; ++c) acc[c] = (f32x4){0.f, 0.f, 0.f, 0.f};

  int rowA = row0 + r; if (rowA >= n) rowA = n - 1;

  for (int ch = 0; ch < 4; ++ch) {
    __syncthreads();
    {
      const char* src = (const char*)Wf + ch * 16384;
      #pragma unroll
      for (int k = 0; k < 4; ++k) {
        float4 v = *(const float4*)(src + k * 4096 + tid * 16);
        *(float4*)(wbuf + k * 4096 + tid * 16) = v;
      }
    }
    __syncthreads();

    #pragma unroll
    for (int lk = 0; lk < 2; ++lk) {
      const int gkt = ch * 2 + lk;
      bf16x8 a;
      if (gkt < 4) a = *(const bf16x8*)(A1 + (size_t)rowA * 128 + gkt * 32 + kb * 8);
      else         a = *(const bf16x8*)(A2 + (size_t)rowA * 128 + (gkt - 4) * 32 + kb * 8);
      #pragma unroll
      for (int c = 0; c < 8; ++c) {
        bf16x8 b = *(const bf16x8*)(wbuf + ((lk * 8 + c) * 64 + lane) * 16);
        acc[c] = __builtin_amdgcn_mfma_f32_16x16x32_bf16(a, b, acc[c], 0, 0, 0);
      }
    }
  }

  #pragma unroll
  for (int c = 0; c < 8; ++c) {
    const int col = c * 16 + r;
    const float bv = bias[col];
    #pragma unroll
    for (int q = 0; q < 4; ++q) {
      int row = row0 + kb * 4 + q;
      if (row < n) {
        float v = elu_fast(acc[c][q] + bv);
        outf[(size_t)row * 128 + col] = v;
      }
    }
  }
}

// ---------------- GCN aggregate v9: fp8 table, 16-edge main + 8-edge mid + masked tail ----------------
// xq[s] already = xg[s]*dinv[s]*128. agg[d] = dinv[d]/128 * ( sum_s xq[s] + xq[d] ) + bgc
__global__ __launch_bounds__(256) void gcn_agg9(
    const int* __restrict__ row_off, const int* __restrict__ csr,
    const float* __restrict__ dinv, const unsigned char* __restrict__ xq,
    const float* __restrict__ bgc, bf16_t* __restrict__ agg, int n)
{
  int w = (int)((blockIdx.x * (unsigned)blockDim.x + threadIdx.x) >> 6);
  if (w >= n) return;
  const int lane = threadIdx.x & 63;
  const int g  = lane >> 4;     // edge subgroup 0..3
  const int li = lane & 15;     // feature octet: cols 8*li .. 8*li+7

  float acc[8];
  #pragma unroll
  for (int j = 0; j < 8; ++j) acc[j] = 0.f;

  if (g == 0) {
    uint2 sv = ((const uint2*)(xq + (size_t)w * 128))[li];
    fp8x8_add(acc, sv);     // self-loop term (dinv[w] already folded)
  }

  const int e0 = row_off[w], e1 = row_off[w + 1];
  int e = e0;
  for (; e + 16 <= e1; e += 16) {
    #pragma unroll
    for (int u = 0; u < 4; ++u) {
      int s = csr[e + 4 * u + g];
      uint2 v = ((const uint2*)(xq + (size_t)s * 128))[li];
      fp8x8_add(acc, v);
    }
  }
  if (e + 8 <= e1) {
    #pragma unroll
    for (int u = 0; u < 2; ++u) {
      int s = csr[e + 4 * u + g];
      uint2 v = ((const uint2*)(xq + (size_t)s * 128))[li];
      fp8x8_add(acc, v);
    }
    e += 8;
  }
  for (; e < e1; e += 4) {
    int idx = e + g;
    int cidx = idx < e1 ? idx : e1 - 1;
    int s = csr[cidx];
    float coef = idx < e1 ? 1.f : 0.f;
    uint2 v = ((const uint2*)(xq + (size_t)s * 128))[li];
    fp8x8_fma(acc, v, coef);
  }

  #pragma unroll
  for (int j = 0; j < 8; ++j) {
    acc[j] += __shfl_xor(acc[j], 16);
    acc[j] += __shfl_xor(acc[j], 32);
  }

  if (g == 0) {
    const float sc = dinv[w] * FP8_ISCL;
    f32x4 b0 = ((const f32x4*)bgc)[2 * li];
    f32x4 b1 = ((const f32x4*)bgc)[2 * li + 1];
    bf16x8 o;
    o[0] = (bf16_t)(acc[0] * sc + b0[0]); o[1] = (bf16_t)(acc[1] * sc + b0[1]);
    o[2] = (bf16_t)(acc[2] * sc + b0[2]); o[3] = (bf16_t)(acc[3] * sc + b0[3]);
    o[4] = (bf16_t)(acc[4] * sc + b1[0]); o[5] = (bf16_t)(acc[5] * sc + b1[1]);
    o[6] = (bf16_t)(acc[6] * sc + b1[2]); o[7] = (bf16_t)(acc[7] * sc + b1[3]);
    ((bf16x8*)(agg + (size_t)w * 128))[li] = o;
  }
}

// ---------------- launch ----------------

extern "C" void kernel_launch(void* const* d_in, const int* in_sizes, int n_in,
                              void* d_out, int out_size, void* d_ws, size_t ws_size,
                              hipStream_t stream) {
  (void)in_sizes; (void)n_in; (void)out_size; (void)ws_size;
  const float* feats = (const float*)d_in[0];
  const int*   edges = (const int*)d_in[1];
  const int*   batch = (const int*)d_in[2];
  const float* W1  = (const float*)d_in[3];
  const float* b1  = (const float*)d_in[4];
  const float* W2  = (const float*)d_in[5];
  const float* b2  = (const float*)d_in[6];
  const float* Wgc = (const float*)d_in[7];
  const float* bgc = (const float*)d_in[8];
  const float* Wc  = (const float*)d_in[9];
  const float* bc  = (const float*)d_in[10];
  float* out = (float*)d_out;

  // workspace layout
  bf16_t* h2b  = (bf16_t*)d_ws;                      // [NN*128] bf16 (nfeats)
  bf16_t* aggb = h2b  + (size_t)NN * 128;            // [NN*128] bf16
  unsigned char* xq8 = (unsigned char*)(aggb + (size_t)NN * 128);  // [NN*128] fp8
  float*  dinv = (float*)(xq8 + (size_t)NN * 128);   // [NN]
  bf16_t* wall = (bf16_t*)(dinv + NN);               // [81920] frag-ordered Ws
  bf16_t* wcf  = wall + 49152;

  // scratch in the FRONT of d_out (dead before final mf_dense_s writes it)
  int* scr     = (int*)d_out;
  int* csr_src = scr;                   // [NE]
  int* row_off = csr_src + NE;          // [NN+1]
  int* H       = row_off + NN + 1;      // [NH]
  int* Hincl   = H + NH;                // [NH]
  int* Hoff    = Hincl + NH;            // [NH+1]
  int* boff    = Hoff + NH + 1;         // [NB1+1]
  int* bsum2   = boff + NB1 + 1;        // [512]
  unsigned int* ebuf = (unsigned int*)(bsum2 + 512);  // [NE] packed (dl<<17|src)

  const int* esrc = edges;
  const int* edst = edges + NE;

  const int nscH = (NH + SB - 1) / SB;   // 151

  // --- CSR build: block-owned bucket sort + fused finalize ---
  histA     <<<NBLK, 256, 0, stream>>>(edst, H, NE);
  scan_blk  <<<nscH, SB, 0, stream>>>(H, Hincl, bsum2, NH);
  scan_top  <<<1, 512, 0, stream>>>(bsum2, nscH);
  scan_add_h<<<nscH, SB, 0, stream>>>(Hincl, H, bsum2, Hoff, boff, NH);
  scatterA  <<<NBLK, 256, 0, stream>>>(esrc, edst, Hoff, ebuf, NE);
  bfin      <<<NB1, 512, 0, stream>>>(ebuf, boff, row_off, dinv, csr_src, NN);

  // --- weight prep (single launch) ---
  wprep4<<<320, 256, 0, stream>>>(W1, W2, Wgc, Wc, wall);

  // --- fused dense 1+2+GCN-linear (64 rows/block, 16 rows/wave, LDS-staged W) ---
  const int nb = (NN + 63) / 64;   // 1563
  mf_dense123<<<nb, 256, 0, stream>>>(feats, wall, b1, b2, dinv, h2b, xq8, NN);

  // --- GCN aggregate (fp8 gather, v9) ---
  long long wthreads = (long long)NN * 64;
  gcn_agg9<<<(int)((wthreads + 255) / 256), 256, 0, stream>>>(
      row_off, csr_src, dinv, xq8, bgc, aggb, NN);

  // --- output layer (fp32 into d_out, overwrites scratch; LDS-staged W) ---
  mf_dense_s<<<nb, 256, 0, stream>>>(h2b, aggb, wcf, bc, out, NN);

  // tail outputs: edges then batch, as float, one launch
  size_t off = (size_t)NN * 128;
  const int ne4 = 2 * NE / 4, ntot4 = (2 * NE + NN) / 4;
  i2f_all<<<(ntot4 + 255) / 256, 256, 0, stream>>>(
      (const int4*)edges, (const int4*)batch, (float4*)(out + off), ne4, ntot4);
}